// Round 13
// baseline (415.654 us; speedup 1.0000x reference)
//
#include <hip/hip_runtime.h>

typedef unsigned short u16;
typedef __attribute__((ext_vector_type(8))) short short8;   // 8 bf16 (4 VGPRs)
typedef __attribute__((ext_vector_type(4))) float f32x4;

__device__ __forceinline__ u16 f2bf(float f) {
    unsigned int x = __float_as_uint(f);
    unsigned int r = x + 0x7fffu + ((x >> 16) & 1u);
    return (u16)(r >> 16);
}
__device__ __forceinline__ unsigned int pk2(float lo, float hi) {
    return ((unsigned int)f2bf(hi) << 16) | (unsigned int)f2bf(lo);
}
__device__ __forceinline__ float2 bf2x(unsigned int d) {
    float2 r;
    r.x = __uint_as_float(d << 16);
    r.y = __uint_as_float(d & 0xffff0000u);
    return r;
}
__device__ __forceinline__ float rfl_f(float x) {
    return __uint_as_float(__builtin_amdgcn_readfirstlane(__float_as_uint(x)));
}

#define CC 96
#define SS 16
#define GG 6
#define BN_INV 0.99999500003749969f  // 1/sqrt(1+1e-5)
#define ABLK 512                     // == 2 blocks/CU exactly (LDS 79.3KB)
#define TOTW (ABLK * 4)

// gWF image (f32): [0..4799] W2E rows L=0..47 (stride 100, Wp2[c'][2L]),
// [4800..9599] W2O (Wp2[c'][2L+1]), [9600..10199] Wwf rows g (Wpw[ch][g]).
#define GWF_W2O 4800
#define GWF_WW  9600
#define GWF_TOT 10200

// ---------------- kernel 0: fused prep (weights repack) + fcvt (feat->bf16) ----------------
__global__ __launch_bounds__(256) void prep_fcvt_kernel(
    const float* __restrict__ feat, u16* __restrict__ featB, int total4,
    const float* __restrict__ Wq, const float* __restrict__ Wk, const float* __restrict__ Wv,
    const float* __restrict__ Wp2, const float* __restrict__ Ww1,
    const float* __restrict__ bp2, const float* __restrict__ bw1,
    u16* __restrict__ WcatT, float* __restrict__ gWF, float* __restrict__ cvec)
{
    int t = blockIdx.x * 256 + threadIdx.x;

    if (t < total4) {
        float4 v = *(const float4*)(feat + (size_t)t * 4);
        ushort4 o;
        o.x = f2bf(v.x); o.y = f2bf(v.y); o.z = f2bf(v.z); o.w = f2bf(v.w);
        *(ushort4*)(featB + (size_t)t * 4) = o;
    }

    if (t < 13824) {
        int c = t / 48, j2 = t % 48;
        const float* src = (c < 96) ? Wq : (c < 192) ? Wk : Wv;
        int cc = c % 96;
        float a = src[(2 * j2) * CC + cc];
        float b = src[(2 * j2 + 1) * CC + cc];
        ((unsigned int*)WcatT)[t] = pk2(a, b);
    } else if (t < 13824 + GWF_TOT) {
        int i = t - 13824;
        if (i < GWF_WW) {
            int half = i / GWF_W2O;          // 0 = even channel, 1 = odd
            int r = i % GWF_W2O;
            int L = r / 100, cp = r % 100;
            float v = 0.f;
            if (cp < 96) v = Wp2[cp * CC + 2 * L + half];
            gWF[i] = v;
        } else {
            int r = i - GWF_WW;
            int g = r / 100, ch = r % 100;
            float v = 0.f;
            if (ch < 96) {
                float a0 = 0.f, a1 = 0.f, a2 = 0.f, a3 = 0.f;
                for (int c = 0; c < CC; c += 4) {
                    a0 = fmaf(Wp2[ch * CC + c + 0], Ww1[(c + 0) * GG + g], a0);
                    a1 = fmaf(Wp2[ch * CC + c + 1], Ww1[(c + 1) * GG + g], a1);
                    a2 = fmaf(Wp2[ch * CC + c + 2], Ww1[(c + 2) * GG + g], a2);
                    a3 = fmaf(Wp2[ch * CC + c + 3], Ww1[(c + 3) * GG + g], a3);
                }
                v = (a0 + a1) + (a2 + a3);
            }
            gWF[i] = v;
        }
    } else if (t < 13824 + GWF_TOT + GG) {
        int g = t - (13824 + GWF_TOT);
        float a0 = bw1[g], a1 = 0.f, a2 = 0.f, a3 = 0.f;
        for (int c = 0; c < CC; c += 4) {
            a0 = fmaf(bp2[c + 0], Ww1[(c + 0) * GG + g], a0);
            a1 = fmaf(bp2[c + 1], Ww1[(c + 1) * GG + g], a1);
            a2 = fmaf(bp2[c + 2], Ww1[(c + 2) * GG + g], a2);
            a3 = fmaf(bp2[c + 3], Ww1[(c + 3) * GG + g], a3);
        }
        cvec[g] = (a0 + a1) + (a2 + a3);
    }
}

// ---------------- kernel 1: fused q|k|v MFMA GEMM + epilogue (r6-proven) ----------------
#define SBS 104
__global__ __launch_bounds__(256, 2) void gemm_qkv(
    const u16* __restrict__ featB, const u16* __restrict__ WcatT,
    const float* __restrict__ bq, const float* __restrict__ gq, const float* __restrict__ betaq,
    const float* __restrict__ bk, const float* __restrict__ gk, const float* __restrict__ betak,
    const float* __restrict__ bv, const float* __restrict__ Ww1,
    u16* __restrict__ v_bf, float* __restrict__ KW1, float* __restrict__ qW1, int N)
{
    __shared__ u16 sB[288 * SBS];
    const int t = threadIdx.x;

    for (int i = t; i < 288 * 12; i += 256) {
        int row = i / 12, c8 = i % 12;
        *(float4*)(sB + row * SBS + c8 * 8) = *(const float4*)(WcatT + row * CC + c8 * 8);
    }
    __syncthreads();

    const int wave = t >> 6, lane = t & 63;
    const int m = lane & 15, quad = lane >> 4;
    const int rowbase = blockIdx.x * 64 + wave * 16;

    int arow = rowbase + m;
    if (arow >= N) arow = 0;

    short8 a[3];
    #pragma unroll
    for (int kk = 0; kk < 3; ++kk)
        a[kk] = *(const short8*)(featB + (size_t)arow * CC + kk * 32 + quad * 8);

    f32x4 acc[18];
    #pragma unroll
    for (int nt = 0; nt < 18; ++nt) acc[nt] = (f32x4){0.f, 0.f, 0.f, 0.f};

    #pragma unroll
    for (int kk = 0; kk < 3; ++kk) {
        #pragma unroll
        for (int nt = 0; nt < 18; ++nt) {
            short8 b = *(const short8*)(sB + (nt * 16 + m) * SBS + kk * 32 + quad * 8);
            acc[nt] = __builtin_amdgcn_mfma_f32_16x16x32_bf16(a[kk], b, acc[nt], 0, 0, 0);
        }
    }

    int orow[4];
    #pragma unroll
    for (int i = 0; i < 4; ++i) orow[i] = rowbase + quad * 4 + i;
    const int cloc = m;

    #pragma unroll
    for (int nt6 = 0; nt6 < 6; ++nt6) {
        int c = nt6 * 16 + cloc;
        float bvv = bv[c];
        #pragma unroll
        for (int i = 0; i < 4; ++i)
            if (orow[i] < N)
                v_bf[(size_t)orow[i] * CC + c] = f2bf(acc[12 + nt6][i] + bvv);
    }

    #pragma unroll
    for (int mat = 0; mat < 2; ++mat) {
        const float* bb_ = mat ? bk : bq;
        const float* gg_ = mat ? gk : gq;
        const float* be_ = mat ? betak : betaq;
        float red[4][6];
        #pragma unroll
        for (int i = 0; i < 4; ++i)
            #pragma unroll
            for (int g = 0; g < 6; ++g) red[i][g] = 0.f;

        #pragma unroll
        for (int nt6 = 0; nt6 < 6; ++nt6) {
            int nt = mat * 6 + nt6;
            int c = nt6 * 16 + cloc;
            float bb = bb_[c], sc = gg_[c] * BN_INV, be = be_[c];
            float w1r[6];
            #pragma unroll
            for (int g = 0; g < 6; ++g) w1r[g] = Ww1[c * GG + g];
            #pragma unroll
            for (int i = 0; i < 4; ++i) {
                float act = fmaxf(0.f, fmaf(acc[nt][i] + bb, sc, be));
                #pragma unroll
                for (int g = 0; g < 6; ++g)
                    red[i][g] = fmaf(act, w1r[g], red[i][g]);
            }
        }
        #pragma unroll
        for (int st = 1; st < 16; st <<= 1)
            #pragma unroll
            for (int i = 0; i < 4; ++i)
                #pragma unroll
                for (int g = 0; g < 6; ++g)
                    red[i][g] += __shfl_xor(red[i][g], st);

        float* dst = mat ? KW1 : qW1;
        #pragma unroll
        for (int g = 0; g < 6; ++g)
            if (cloc == g)
                #pragma unroll
                for (int i = 0; i < 4; ++i)
                    if (orow[i] < N)
                        dst[(size_t)orow[i] * 8 + g] = red[i][g];
    }
}

// ---------------- kernel 2: attention v15 — r7/r12 + reg-hoisted stage-5 weights + rcp softmax ----------------
// Occupancy fixed at 2 waves/SIMD (power-of-2 VGPR tiers; caps spill; LDS squeeze
// fails). The 129-256 tier leaves ~110 VGPRs free at zero occupancy cost — spend
// them: stage-5's per-lane Wp2 rows are loop-INVARIANT but re-read from LDS every
// point (48 ds_read_b128/pt). Hoist u=0..5 (24 float4 = 96 VGPR) into registers,
// deleting 24 DS issues/pt. Softmax divides -> v_rcp_f32+mul (err 2^-22 << 2^-9).
__global__ __launch_bounds__(256) void attn_kernel(
    const float* __restrict__ coord, const int* __restrict__ ref,
    const float* __restrict__ Wp1, const float* __restrict__ bp1, const float* __restrict__ gp, const float* __restrict__ betap,
    const float* __restrict__ bp2,
    const float* __restrict__ gw, const float* __restrict__ betaw,
    const float* __restrict__ Ww2, const float* __restrict__ bw2,
    const u16* __restrict__ v_bf, const float* __restrict__ KW1, const float* __restrict__ qW1,
    const float* __restrict__ gWF, const float* __restrict__ cvec,
    float* __restrict__ out, int N)
{
    __shared__ __align__(16) float sWF[GWF_TOT];        // 40800 B: W2E | W2O | Wwf
    __shared__ __align__(16) float shh[4][SS * 100];    // 25600 B  h f32 [s*100 + 2L]
    __shared__ __align__(16) float swtf[4][SS * 8];     // 2048 B   softmax wgt f32 [s*8+g]
    __shared__ __align__(16) float sHs[4][600];         // 9600 B   Hsum [g*100 + 2L]
    __shared__ __align__(16) float4 sposx[4][SS];       // 1024 B
    __shared__ int sidxx[4][SS];                        // 256 B
    // total 79328 B -> 2 blocks/CU

    const int t = threadIdx.x;
    for (int i = t; i < GWF_TOT; i += 256) sWF[i] = gWF[i];
    __syncthreads();   // only block barrier

    const int w = t >> 6, lane = t & 63;
    const int wid = blockIdx.x * 4 + w;
    float* shw = shh[w];
    float* swtw = swtf[w];
    float* sHsw = sHs[w];
    float4* sposw = sposx[w];
    int* sidxw = sidxx[w];

    const int  L = (lane < 48) ? lane : 47;
    const bool actv = lane < 48;
    const int  cA = 2 * L;
    const int  gL = L >> 3;
    const int  s16 = lane & 15, qq = lane >> 4;

    const float spA = gp[cA] * BN_INV, spB = gp[cA + 1] * BN_INV;
    const float w1xA = Wp1[cA] * spA, w1yA = Wp1[CC + cA] * spA, w1zA = Wp1[2 * CC + cA] * spA;
    const float w1xB = Wp1[cA + 1] * spB, w1yB = Wp1[CC + cA + 1] * spB, w1zB = Wp1[2 * CC + cA + 1] * spB;
    const float b1A = fmaf(bp1[cA], spA, betap[cA]);
    const float b1B = fmaf(bp1[cA + 1], spB, betap[cA + 1]);
    const float bpA = bp2[cA], bpB = bp2[cA + 1];

    const float* wE = sWF + L * 100;             // even channel cA
    const float* wO = sWF + GWF_W2O + L * 100;   // odd channel cA+1

    // hoisted stage-5 weights for u=0..5 (loop-invariant; 96 VGPR, free in tier)
    float4 wEr0[6], wEr1[6], wOr0[6], wOr1[6];
    #pragma unroll
    for (int u = 0; u < 6; ++u) {
        wEr0[u] = *(const float4*)(wE + 8 * u);
        wEr1[u] = *(const float4*)(wE + 8 * u + 4);
        wOr0[u] = *(const float4*)(wO + 8 * u);
        wOr1[u] = *(const float4*)(wO + 8 * u + 4);
    }

    int idxreg = 0;
    if (lane < SS && wid < N) idxreg = ref[wid * SS + s16];

    for (int n = wid; n < N; n += TOTW) {
        // ---- head: indices, pos, k-row gather ----
        if (lane < SS) sidxw[s16] = idxreg;
        float4 kAv = {0,0,0,0}; float2 kBv = {0,0};
        if (lane < SS) {
            int j = idxreg;
            float4 P;
            P.x = coord[j * 3 + 0] - coord[n * 3 + 0];
            P.y = coord[j * 3 + 1] - coord[n * 3 + 1];
            P.z = coord[j * 3 + 2] - coord[n * 3 + 2];
            P.w = 0.f;
            sposw[s16] = P;
            const float* kr = KW1 + (size_t)idxreg * 8;
            kAv = *(const float4*)kr; kBv = *(const float2*)(kr + 4);
        }
        float qc[GG];
        {
            int nu = __builtin_amdgcn_readfirstlane(n);
            const float* qr = qW1 + (size_t)nu * 8;
            #pragma unroll
            for (int g = 0; g < GG; ++g)
                qc[g] = rfl_f(cvec[g] - qr[g]);
        }
        {
            int nn = n + TOTW;
            if (lane < SS && nn < N) idxreg = ref[nn * SS + s16];
        }

        // ---- stage 1 ----
        if (actv) {
            #pragma unroll
            for (int s = 0; s < SS; ++s) {
                float4 P = sposw[s];
                float hA = fmaxf(0.f, fmaf(P.x, w1xA, fmaf(P.y, w1yA, fmaf(P.z, w1zA, b1A))));
                float hB = fmaxf(0.f, fmaf(P.x, w1xB, fmaf(P.y, w1yB, fmaf(P.z, w1zB, b1B))));
                *(float2*)(shw + s * 100 + cA) = make_float2(hA, hB);
            }
        }

        // ---- stage 2 main ----
        float acc[GG];
        {
            const float* hrow = shw + 100 * s16 + 24 * qq;
            const float* wbase = sWF + GWF_WW + 24 * qq;
            #pragma unroll
            for (int g = 0; g < GG; ++g) acc[g] = 0.f;
            #pragma unroll
            for (int c3 = 0; c3 < 3; ++c3) {
                float4 h0 = *(const float4*)(hrow + 8 * c3);
                float4 h1 = *(const float4*)(hrow + 8 * c3 + 4);
                #pragma unroll
                for (int g = 0; g < GG; ++g) {
                    const float* wr = wbase + g * 100 + 8 * c3;
                    float4 w0 = *(const float4*)(wr);
                    float4 w1 = *(const float4*)(wr + 4);
                    float a = acc[g];
                    a = fmaf(h0.x, w0.x, a); a = fmaf(h0.y, w0.y, a);
                    a = fmaf(h0.z, w0.z, a); a = fmaf(h0.w, w0.w, a);
                    a = fmaf(h1.x, w1.x, a); a = fmaf(h1.y, w1.y, a);
                    a = fmaf(h1.z, w1.z, a); a = fmaf(h1.w, w1.w, a);
                    acc[g] = a;
                }
            }
            #pragma unroll
            for (int g = 0; g < GG; ++g) {
                acc[g] += __shfl_xor(acc[g], 16);
                acc[g] += __shfl_xor(acc[g], 32);
            }
        }

        // ---- v gather ----
        unsigned int vpre[SS];
        #pragma unroll
        for (int s = 0; s < SS; ++s) {
            int jj = sidxw[s];
            vpre[s] = *(const unsigned int*)(v_bf + (size_t)jj * CC + cA);
        }

        // ---- stage 2 epilogue: softmax (lanes < 16) ----
        if (lane < SS) {
            float tv[GG];
            tv[0] = acc[0] + kAv.x + qc[0];
            tv[1] = acc[1] + kAv.y + qc[1];
            tv[2] = acc[2] + kAv.z + qc[2];
            tv[3] = acc[3] + kAv.w + qc[3];
            tv[4] = acc[4] + kBv.x + qc[4];
            tv[5] = acc[5] + kBv.y + qc[5];
            float a6[GG];
            #pragma unroll
            for (int g = 0; g < GG; ++g)
                a6[g] = fmaxf(0.f, fmaf(tv[g], gw[g] * BN_INV, betaw[g]));
            float e[GG];
            #pragma unroll
            for (int gg2 = 0; gg2 < GG; ++gg2) {
                float lv = bw2[gg2];
                #pragma unroll
                for (int g2 = 0; g2 < GG; ++g2)
                    lv = fmaf(a6[g2], Ww2[g2 * GG + gg2], lv);
                e[gg2] = __expf(lv);
            }
            float wgt[GG];
            #pragma unroll
            for (int g = 0; g < GG; ++g) {
                float ssum = e[g];
                ssum += __shfl_xor(ssum, 1);
                ssum += __shfl_xor(ssum, 2);
                ssum += __shfl_xor(ssum, 4);
                ssum += __shfl_xor(ssum, 8);
                wgt[g] = e[g] * __builtin_amdgcn_rcpf(ssum);   // rcp+mul, not full div
            }
            float4 wt03; wt03.x = wgt[0]; wt03.y = wgt[1]; wt03.z = wgt[2]; wt03.w = wgt[3];
            *(float4*)(swtw + s16 * 8) = wt03;
            *(float2*)(swtw + s16 * 8 + 4) = make_float2(wgt[4], wgt[5]);
        }

        // ---- stage 3+4 ----
        float accA = bpA, accB = bpB;
        {
            float hsA[GG] = {0.f,0.f,0.f,0.f,0.f,0.f};
            float hsB[GG] = {0.f,0.f,0.f,0.f,0.f,0.f};
            #pragma unroll
            for (int s = 0; s < SS; ++s) {
                float4 w03 = *(const float4*)(swtw + s * 8);
                float2 w45 = *(const float2*)(swtw + s * 8 + 4);
                float wsel = swtw[s * 8 + gL];
                float2 h2 = *(const float2*)(shw + s * 100 + cA);
                hsA[0] = fmaf(w03.x, h2.x, hsA[0]); hsB[0] = fmaf(w03.x, h2.y, hsB[0]);
                hsA[1] = fmaf(w03.y, h2.x, hsA[1]); hsB[1] = fmaf(w03.y, h2.y, hsB[1]);
                hsA[2] = fmaf(w03.z, h2.x, hsA[2]); hsB[2] = fmaf(w03.z, h2.y, hsB[2]);
                hsA[3] = fmaf(w03.w, h2.x, hsA[3]); hsB[3] = fmaf(w03.w, h2.y, hsB[3]);
                hsA[4] = fmaf(w45.x, h2.x, hsA[4]); hsB[4] = fmaf(w45.x, h2.y, hsB[4]);
                hsA[5] = fmaf(w45.y, h2.x, hsA[5]); hsB[5] = fmaf(w45.y, h2.y, hsB[5]);
                float2 v2 = bf2x(vpre[s]);
                accA = fmaf(v2.x, wsel, accA);
                accB = fmaf(v2.y, wsel, accB);
            }
            if (actv) {
                #pragma unroll
                for (int g = 0; g < GG; ++g)
                    *(float2*)(sHsw + g * 100 + cA) = make_float2(hsA[g], hsB[g]);
            }
        }

        // ---- stage 5 (u<6 weights from registers, u>=6 from LDS) ----
        if (actv) {
            const float* hrg = sHsw + gL * 100;
            #pragma unroll
            for (int u = 0; u < 12; ++u) {
                float4 hb0 = *(const float4*)(hrg + 8 * u);
                float4 hb1 = *(const float4*)(hrg + 8 * u + 4);
                float4 we0, we1, wo0, wo1;
                if (u < 6) {
                    we0 = wEr0[u]; we1 = wEr1[u];
                    wo0 = wOr0[u]; wo1 = wOr1[u];
                } else {
                    we0 = *(const float4*)(wE + 8 * u);
                    we1 = *(const float4*)(wE + 8 * u + 4);
                    wo0 = *(const float4*)(wO + 8 * u);
                    wo1 = *(const float4*)(wO + 8 * u + 4);
                }
                accA = fmaf(hb0.x, we0.x, accA); accB = fmaf(hb0.x, wo0.x, accB);
                accA = fmaf(hb0.y, we0.y, accA); accB = fmaf(hb0.y, wo0.y, accB);
                accA = fmaf(hb0.z, we0.z, accA); accB = fmaf(hb0.z, wo0.z, accB);
                accA = fmaf(hb0.w, we0.w, accA); accB = fmaf(hb0.w, wo0.w, accB);
                accA = fmaf(hb1.x, we1.x, accA); accB = fmaf(hb1.x, wo1.x, accB);
                accA = fmaf(hb1.y, we1.y, accA); accB = fmaf(hb1.y, wo1.y, accB);
                accA = fmaf(hb1.z, we1.z, accA); accB = fmaf(hb1.z, wo1.z, accB);
                accA = fmaf(hb1.w, we1.w, accA); accB = fmaf(hb1.w, wo1.w, accB);
            }
            *(float2*)(out + (size_t)n * CC + cA) = make_float2(accA, accB);
        }
    }
}

extern "C" void kernel_launch(void* const* d_in, const int* in_sizes, int n_in,
                              void* d_out, int out_size, void* d_ws, size_t ws_size,
                              hipStream_t stream) {
    const float* feat  = (const float*)d_in[0];
    const float* coord = (const float*)d_in[1];
    const int*   ref   = (const int*)d_in[2];
    const float* Wq = (const float*)d_in[3],  *bq = (const float*)d_in[4],  *gq = (const float*)d_in[5],  *betaq = (const float*)d_in[6];
    const float* Wk = (const float*)d_in[7],  *bk = (const float*)d_in[8],  *gk = (const float*)d_in[9],  *betak = (const float*)d_in[10];
    const float* Wv = (const float*)d_in[11], *bv = (const float*)d_in[12];
    const float* Wp1 = (const float*)d_in[13], *bp1 = (const float*)d_in[14], *gp = (const float*)d_in[15], *betap = (const float*)d_in[16];
    const float* Wp2 = (const float*)d_in[17], *bp2 = (const float*)d_in[18];
    const float* Ww1 = (const float*)d_in[19], *bw1 = (const float*)d_in[20], *gw = (const float*)d_in[21], *betaw = (const float*)d_in[22];
    const float* Ww2 = (const float*)d_in[23], *bw2 = (const float*)d_in[24];

    const int N = in_sizes[0] / CC;   // 50000

    float* wsf = (float*)d_ws;
    float* KW1 = wsf;                                  // N*8 f32
    float* qW1 = KW1 + (size_t)N * 8;                  // N*8 f32
    float* cvec = qW1 + (size_t)N * 8;                 // 6 (pad 32)
    float* gWF = cvec + 32;                            // 10200 (pad 10240)
    u16* WcatT = (u16*)(gWF + 10240);                  // 288*96 bf16
    u16* featB = WcatT + 288 * CC;                     // N*96 bf16
    u16* v_bf = featB + (size_t)N * CC;                // N*96 bf16

    const int total4 = N * CC / 4;
    prep_fcvt_kernel<<<dim3((total4 + 255) / 256), dim3(256), 0, stream>>>(
        feat, featB, total4,
        Wq, Wk, Wv, Wp2, Ww1, bp2, bw1, WcatT, gWF, cvec);

    gemm_qkv<<<dim3((N + 63) / 64), dim3(256), 0, stream>>>(
        featB, WcatT, bq, gq, betaq, bk, gk, betak, bv, Ww1,
        v_bf, KW1, qW1, N);

    attn_kernel<<<dim3(ABLK), dim3(256), 0, stream>>>(
        coord, ref, Wp1, bp1, gp, betap, bp2, gw, betaw, Ww2, bw2,
        v_bf, KW1, qW1, gWF, cvec, (float*)d_out, N);
}

// Round 14
// 384.247 us; speedup vs baseline: 1.0817x; 1.0817x over previous
//
#include <hip/hip_runtime.h>

typedef unsigned short u16;
typedef __attribute__((ext_vector_type(8))) short short8;   // 8 bf16 (4 VGPRs)
typedef __attribute__((ext_vector_type(4))) float f32x4;

__device__ __forceinline__ u16 f2bf(float f) {
    unsigned int x = __float_as_uint(f);
    unsigned int r = x + 0x7fffu + ((x >> 16) & 1u);
    return (u16)(r >> 16);
}
__device__ __forceinline__ unsigned int pk2(float lo, float hi) {
    return ((unsigned int)f2bf(hi) << 16) | (unsigned int)f2bf(lo);
}
__device__ __forceinline__ float2 bf2x(unsigned int d) {
    float2 r;
    r.x = __uint_as_float(d << 16);
    r.y = __uint_as_float(d & 0xffff0000u);
    return r;
}
__device__ __forceinline__ float rfl_f(float x) {
    return __uint_as_float(__builtin_amdgcn_readfirstlane(__float_as_uint(x)));
}

#define CC 96
#define SS 16
#define GG 6
#define BN_INV 0.99999500003749969f  // 1/sqrt(1+1e-5)
#define ABLK 512                     // == 2 blocks/CU exactly (VGPR 136, LDS 79.3KB)
#define TOTW (ABLK * 4)

// gWF image (f32): [0..4799] W2E rows L=0..47 (stride 100, Wp2[c'][2L]),
// [4800..9599] W2O (Wp2[c'][2L+1]), [9600..10199] Wwf rows g (Wpw[ch][g]).
#define GWF_W2O 4800
#define GWF_WW  9600
#define GWF_TOT 10200

// ---------------- kernel 0: fused prep (weights repack) + fcvt (feat->bf16) ----------------
// r12-proven. Session history (r1-r13): occupancy tiers are power-of-2 only
// (2 waves/SIMD for VGPR 129-256); every forced cap spills catastrophically;
// LDS 3-block squeeze misses the pool by less than the driver reserve;
// gather-cover pipelining regresses (gathers already covered); register-hoisting
// LDS reads regresses (scheduling degrades with pressure). The two wins:
// f32 LDS operands (r7, -35us) and this prep fusion (r12).
__global__ __launch_bounds__(256) void prep_fcvt_kernel(
    const float* __restrict__ feat, u16* __restrict__ featB, int total4,
    const float* __restrict__ Wq, const float* __restrict__ Wk, const float* __restrict__ Wv,
    const float* __restrict__ Wp2, const float* __restrict__ Ww1,
    const float* __restrict__ bp2, const float* __restrict__ bw1,
    u16* __restrict__ WcatT, float* __restrict__ gWF, float* __restrict__ cvec)
{
    int t = blockIdx.x * 256 + threadIdx.x;

    // ---- fcvt part (memory-bound bulk) ----
    if (t < total4) {
        float4 v = *(const float4*)(feat + (size_t)t * 4);
        ushort4 o;
        o.x = f2bf(v.x); o.y = f2bf(v.y); o.z = f2bf(v.z); o.w = f2bf(v.w);
        *(ushort4*)(featB + (size_t)t * 4) = o;
    }

    // ---- prep part (first 24030 threads also do this; disjoint outputs) ----
    if (t < 13824) {
        int c = t / 48, j2 = t % 48;
        const float* src = (c < 96) ? Wq : (c < 192) ? Wk : Wv;
        int cc = c % 96;
        float a = src[(2 * j2) * CC + cc];
        float b = src[(2 * j2 + 1) * CC + cc];
        ((unsigned int*)WcatT)[t] = pk2(a, b);
    } else if (t < 13824 + GWF_TOT) {
        int i = t - 13824;
        if (i < GWF_WW) {
            int half = i / GWF_W2O;          // 0 = even channel, 1 = odd
            int r = i % GWF_W2O;
            int L = r / 100, cp = r % 100;
            float v = 0.f;
            if (cp < 96) v = Wp2[cp * CC + 2 * L + half];
            gWF[i] = v;
        } else {
            int r = i - GWF_WW;
            int g = r / 100, ch = r % 100;
            float v = 0.f;
            if (ch < 96) {
                float a0 = 0.f, a1 = 0.f, a2 = 0.f, a3 = 0.f;
                for (int c = 0; c < CC; c += 4) {
                    a0 = fmaf(Wp2[ch * CC + c + 0], Ww1[(c + 0) * GG + g], a0);
                    a1 = fmaf(Wp2[ch * CC + c + 1], Ww1[(c + 1) * GG + g], a1);
                    a2 = fmaf(Wp2[ch * CC + c + 2], Ww1[(c + 2) * GG + g], a2);
                    a3 = fmaf(Wp2[ch * CC + c + 3], Ww1[(c + 3) * GG + g], a3);
                }
                v = (a0 + a1) + (a2 + a3);
            }
            gWF[i] = v;
        }
    } else if (t < 13824 + GWF_TOT + GG) {
        int g = t - (13824 + GWF_TOT);
        float a0 = bw1[g], a1 = 0.f, a2 = 0.f, a3 = 0.f;
        for (int c = 0; c < CC; c += 4) {
            a0 = fmaf(bp2[c + 0], Ww1[(c + 0) * GG + g], a0);
            a1 = fmaf(bp2[c + 1], Ww1[(c + 1) * GG + g], a1);
            a2 = fmaf(bp2[c + 2], Ww1[(c + 2) * GG + g], a2);
            a3 = fmaf(bp2[c + 3], Ww1[(c + 3) * GG + g], a3);
        }
        cvec[g] = (a0 + a1) + (a2 + a3);
    }
}

// ---------------- kernel 1: fused q|k|v MFMA GEMM + epilogue (r6-proven) ----------------
#define SBS 104
__global__ __launch_bounds__(256, 2) void gemm_qkv(
    const u16* __restrict__ featB, const u16* __restrict__ WcatT,
    const float* __restrict__ bq, const float* __restrict__ gq, const float* __restrict__ betaq,
    const float* __restrict__ bk, const float* __restrict__ gk, const float* __restrict__ betak,
    const float* __restrict__ bv, const float* __restrict__ Ww1,
    u16* __restrict__ v_bf, float* __restrict__ KW1, float* __restrict__ qW1, int N)
{
    __shared__ u16 sB[288 * SBS];
    const int t = threadIdx.x;

    for (int i = t; i < 288 * 12; i += 256) {
        int row = i / 12, c8 = i % 12;
        *(float4*)(sB + row * SBS + c8 * 8) = *(const float4*)(WcatT + row * CC + c8 * 8);
    }
    __syncthreads();

    const int wave = t >> 6, lane = t & 63;
    const int m = lane & 15, quad = lane >> 4;
    const int rowbase = blockIdx.x * 64 + wave * 16;

    int arow = rowbase + m;
    if (arow >= N) arow = 0;

    short8 a[3];
    #pragma unroll
    for (int kk = 0; kk < 3; ++kk)
        a[kk] = *(const short8*)(featB + (size_t)arow * CC + kk * 32 + quad * 8);

    f32x4 acc[18];
    #pragma unroll
    for (int nt = 0; nt < 18; ++nt) acc[nt] = (f32x4){0.f, 0.f, 0.f, 0.f};

    #pragma unroll
    for (int kk = 0; kk < 3; ++kk) {
        #pragma unroll
        for (int nt = 0; nt < 18; ++nt) {
            short8 b = *(const short8*)(sB + (nt * 16 + m) * SBS + kk * 32 + quad * 8);
            acc[nt] = __builtin_amdgcn_mfma_f32_16x16x32_bf16(a[kk], b, acc[nt], 0, 0, 0);
        }
    }

    int orow[4];
    #pragma unroll
    for (int i = 0; i < 4; ++i) orow[i] = rowbase + quad * 4 + i;
    const int cloc = m;

    #pragma unroll
    for (int nt6 = 0; nt6 < 6; ++nt6) {
        int c = nt6 * 16 + cloc;
        float bvv = bv[c];
        #pragma unroll
        for (int i = 0; i < 4; ++i)
            if (orow[i] < N)
                v_bf[(size_t)orow[i] * CC + c] = f2bf(acc[12 + nt6][i] + bvv);
    }

    #pragma unroll
    for (int mat = 0; mat < 2; ++mat) {
        const float* bb_ = mat ? bk : bq;
        const float* gg_ = mat ? gk : gq;
        const float* be_ = mat ? betak : betaq;
        float red[4][6];
        #pragma unroll
        for (int i = 0; i < 4; ++i)
            #pragma unroll
            for (int g = 0; g < 6; ++g) red[i][g] = 0.f;

        #pragma unroll
        for (int nt6 = 0; nt6 < 6; ++nt6) {
            int nt = mat * 6 + nt6;
            int c = nt6 * 16 + cloc;
            float bb = bb_[c], sc = gg_[c] * BN_INV, be = be_[c];
            float w1r[6];
            #pragma unroll
            for (int g = 0; g < 6; ++g) w1r[g] = Ww1[c * GG + g];
            #pragma unroll
            for (int i = 0; i < 4; ++i) {
                float act = fmaxf(0.f, fmaf(acc[nt][i] + bb, sc, be));
                #pragma unroll
                for (int g = 0; g < 6; ++g)
                    red[i][g] = fmaf(act, w1r[g], red[i][g]);
            }
        }
        #pragma unroll
        for (int st = 1; st < 16; st <<= 1)
            #pragma unroll
            for (int i = 0; i < 4; ++i)
                #pragma unroll
                for (int g = 0; g < 6; ++g)
                    red[i][g] += __shfl_xor(red[i][g], st);

        float* dst = mat ? KW1 : qW1;
        #pragma unroll
        for (int g = 0; g < 6; ++g)
            if (cloc == g)
                #pragma unroll
                for (int i = 0; i < 4; ++i)
                    if (orow[i] < N)
                        dst[(size_t)orow[i] * 8 + g] = red[i][g];
    }
}

// ---------------- kernel 2: attention v11 (r7/r12 exact — session best, 252us) ----------------
// f32 LDS operands (VALU de-bloat): ~600 of ~2750 VALU ops/point were bf16
// pack/unpack + select chains on LDS-resident data; all LDS operands f32.
// LDS 79.3KB -> 2 blocks/CU. Do NOT: hoist stage-5 weights to registers (r13:
// VGPR 180 + spill, +32us), cap VGPRs (r1/r3/r4: catastrophic spill), stage v
// in LDS (r5: +50us), move weights to L2 (r11: +68us), pipeline gathers (r8: +22us).
__global__ __launch_bounds__(256) void attn_kernel(
    const float* __restrict__ coord, const int* __restrict__ ref,
    const float* __restrict__ Wp1, const float* __restrict__ bp1, const float* __restrict__ gp, const float* __restrict__ betap,
    const float* __restrict__ bp2,
    const float* __restrict__ gw, const float* __restrict__ betaw,
    const float* __restrict__ Ww2, const float* __restrict__ bw2,
    const u16* __restrict__ v_bf, const float* __restrict__ KW1, const float* __restrict__ qW1,
    const float* __restrict__ gWF, const float* __restrict__ cvec,
    float* __restrict__ out, int N)
{
    __shared__ __align__(16) float sWF[GWF_TOT];        // 40800 B: W2E | W2O | Wwf
    __shared__ __align__(16) float shh[4][SS * 100];    // 25600 B  h f32 [s*100 + 2L]
    __shared__ __align__(16) float swtf[4][SS * 8];     // 2048 B   softmax wgt f32 [s*8+g]
    __shared__ __align__(16) float sHs[4][600];         // 9600 B   Hsum [g*100 + 2L]
    __shared__ __align__(16) float4 sposx[4][SS];       // 1024 B
    __shared__ int sidxx[4][SS];                        // 256 B
    // total 79328 B -> 2 blocks/CU

    const int t = threadIdx.x;
    for (int i = t; i < GWF_TOT; i += 256) sWF[i] = gWF[i];
    __syncthreads();   // only block barrier

    const int w = t >> 6, lane = t & 63;
    const int wid = blockIdx.x * 4 + w;
    float* shw = shh[w];
    float* swtw = swtf[w];
    float* sHsw = sHs[w];
    float4* sposw = sposx[w];
    int* sidxw = sidxx[w];

    const int  L = (lane < 48) ? lane : 47;
    const bool actv = lane < 48;
    const int  cA = 2 * L;
    const int  gL = L >> 3;
    const int  s16 = lane & 15, qq = lane >> 4;

    // BN folded into Wp1: h = relu(sp*(dot+b1) + bt) = relu(dot' + b1')
    const float spA = gp[cA] * BN_INV, spB = gp[cA + 1] * BN_INV;
    const float w1xA = Wp1[cA] * spA, w1yA = Wp1[CC + cA] * spA, w1zA = Wp1[2 * CC + cA] * spA;
    const float w1xB = Wp1[cA + 1] * spB, w1yB = Wp1[CC + cA + 1] * spB, w1zB = Wp1[2 * CC + cA + 1] * spB;
    const float b1A = fmaf(bp1[cA], spA, betap[cA]);
    const float b1B = fmaf(bp1[cA + 1], spB, betap[cA + 1]);
    const float bpA = bp2[cA], bpB = bp2[cA + 1];

    // prefetched ref indices for the upcoming iteration
    int idxreg = 0;
    if (lane < SS && wid < N) idxreg = ref[wid * SS + s16];

    for (int n = wid; n < N; n += TOTW) {
        // ---- head: indices, pos, k-row gather ----
        if (lane < SS) sidxw[s16] = idxreg;
        float4 kAv = {0,0,0,0}; float2 kBv = {0,0};
        if (lane < SS) {
            int j = idxreg;
            float4 P;
            P.x = coord[j * 3 + 0] - coord[n * 3 + 0];
            P.y = coord[j * 3 + 1] - coord[n * 3 + 1];
            P.z = coord[j * 3 + 2] - coord[n * 3 + 2];
            P.w = 0.f;
            sposw[s16] = P;
            const float* kr = KW1 + (size_t)idxreg * 8;
            kAv = *(const float4*)kr; kBv = *(const float2*)(kr + 4);
        }
        // uniform q-row: fold cvec - q into SGPRs (n is wave-uniform)
        float qc[GG];
        {
            int nu = __builtin_amdgcn_readfirstlane(n);
            const float* qr = qW1 + (size_t)nu * 8;
            #pragma unroll
            for (int g = 0; g < GG; ++g)
                qc[g] = rfl_f(cvec[g] - qr[g]);
        }
        // issue next iteration's ref load now; result consumed next iteration
        {
            int nn = n + TOTW;
            if (lane < SS && nn < N) idxreg = ref[nn * SS + s16];
        }

        // ---- stage 1: h = relu(pos@Wp1' + b1') -> f32 pairs in LDS ----
        if (actv) {
            #pragma unroll
            for (int s = 0; s < SS; ++s) {
                float4 P = sposw[s];                 // broadcast b128
                float hA = fmaxf(0.f, fmaf(P.x, w1xA, fmaf(P.y, w1yA, fmaf(P.z, w1zA, b1A))));
                float hB = fmaxf(0.f, fmaf(P.x, w1xB, fmaf(P.y, w1yB, fmaf(P.z, w1zB, b1B))));
                *(float2*)(shw + s * 100 + cA) = make_float2(hA, hB);
            }
        }

        // ---- stage 2 main: logits, f32 operands, 8-channel chunks ----
        float acc[GG];
        {
            const float* hrow = shw + 100 * s16 + 24 * qq;
            const float* wbase = sWF + GWF_WW + 24 * qq;
            #pragma unroll
            for (int g = 0; g < GG; ++g) acc[g] = 0.f;
            #pragma unroll
            for (int c3 = 0; c3 < 3; ++c3) {
                float4 h0 = *(const float4*)(hrow + 8 * c3);
                float4 h1 = *(const float4*)(hrow + 8 * c3 + 4);
                #pragma unroll
                for (int g = 0; g < GG; ++g) {
                    const float* wr = wbase + g * 100 + 8 * c3;
                    float4 w0 = *(const float4*)(wr);      // broadcast (4 addrs/wave)
                    float4 w1 = *(const float4*)(wr + 4);
                    float a = acc[g];
                    a = fmaf(h0.x, w0.x, a); a = fmaf(h0.y, w0.y, a);
                    a = fmaf(h0.z, w0.z, a); a = fmaf(h0.w, w0.w, a);
                    a = fmaf(h1.x, w1.x, a); a = fmaf(h1.y, w1.y, a);
                    a = fmaf(h1.z, w1.z, a); a = fmaf(h1.w, w1.w, a);
                    acc[g] = a;
                }
            }
            #pragma unroll
            for (int g = 0; g < GG; ++g) {
                acc[g] += __shfl_xor(acc[g], 16);
                acc[g] += __shfl_xor(acc[g], 32);
            }
        }

        // ---- v gather (kept out of the stage-2 register peak) ----
        unsigned int vpre[SS];
        #pragma unroll
        for (int s = 0; s < SS; ++s) {
            int jj = sidxw[s];                       // wave-private, in-order DS
            vpre[s] = *(const unsigned int*)(v_bf + (size_t)jj * CC + cA);
        }

        // ---- stage 2 epilogue: softmax weights (lanes < 16), f32 to LDS ----
        if (lane < SS) {
            float tv[GG];
            tv[0] = acc[0] + kAv.x + qc[0];
            tv[1] = acc[1] + kAv.y + qc[1];
            tv[2] = acc[2] + kAv.z + qc[2];
            tv[3] = acc[3] + kAv.w + qc[3];
            tv[4] = acc[4] + kBv.x + qc[4];
            tv[5] = acc[5] + kBv.y + qc[5];
            float a6[GG];
            #pragma unroll
            for (int g = 0; g < GG; ++g)
                a6[g] = fmaxf(0.f, fmaf(tv[g], gw[g] * BN_INV, betaw[g]));
            float e[GG];
            #pragma unroll
            for (int gg2 = 0; gg2 < GG; ++gg2) {
                float lv = bw2[gg2];
                #pragma unroll
                for (int g2 = 0; g2 < GG; ++g2)
                    lv = fmaf(a6[g2], Ww2[g2 * GG + gg2], lv);
                e[gg2] = __expf(lv);
            }
            float wgt[GG];
            #pragma unroll
            for (int g = 0; g < GG; ++g) {
                float ssum = e[g];
                ssum += __shfl_xor(ssum, 1);
                ssum += __shfl_xor(ssum, 2);
                ssum += __shfl_xor(ssum, 4);
                ssum += __shfl_xor(ssum, 8);
                wgt[g] = e[g] / ssum;
            }
            float4 wt03; wt03.x = wgt[0]; wt03.y = wgt[1]; wt03.z = wgt[2]; wt03.w = wgt[3];
            *(float4*)(swtw + s16 * 8) = wt03;
            *(float2*)(swtw + s16 * 8 + 4) = make_float2(wgt[4], wgt[5]);
        }

        // ---- stage 3+4: Hsum + v-part fused (f32 wgt/h, no unpack/select) ----
        float accA = bpA, accB = bpB;
        {
            float hsA[GG] = {0.f,0.f,0.f,0.f,0.f,0.f};
            float hsB[GG] = {0.f,0.f,0.f,0.f,0.f,0.f};
            #pragma unroll
            for (int s = 0; s < SS; ++s) {
                float4 w03 = *(const float4*)(swtw + s * 8);   // broadcast
                float2 w45 = *(const float2*)(swtw + s * 8 + 4);
                float wsel = swtw[s * 8 + gL];                 // 6 addrs, broadcast groups
                float2 h2 = *(const float2*)(shw + s * 100 + cA);
                hsA[0] = fmaf(w03.x, h2.x, hsA[0]); hsB[0] = fmaf(w03.x, h2.y, hsB[0]);
                hsA[1] = fmaf(w03.y, h2.x, hsA[1]); hsB[1] = fmaf(w03.y, h2.y, hsB[1]);
                hsA[2] = fmaf(w03.z, h2.x, hsA[2]); hsB[2] = fmaf(w03.z, h2.y, hsB[2]);
                hsA[3] = fmaf(w03.w, h2.x, hsA[3]); hsB[3] = fmaf(w03.w, h2.y, hsB[3]);
                hsA[4] = fmaf(w45.x, h2.x, hsA[4]); hsB[4] = fmaf(w45.x, h2.y, hsB[4]);
                hsA[5] = fmaf(w45.y, h2.x, hsA[5]); hsB[5] = fmaf(w45.y, h2.y, hsB[5]);
                float2 v2 = bf2x(vpre[s]);
                accA = fmaf(v2.x, wsel, accA);
                accB = fmaf(v2.y, wsel, accB);
            }
            if (actv) {
                #pragma unroll
                for (int g = 0; g < GG; ++g)
                    *(float2*)(sHsw + g * 100 + cA) = make_float2(hsA[g], hsB[g]);
            }
        }

        // ---- stage 5: out = v-part + Hsum[gL] @ Wp2 cols (f32 E/O copies) ----
        if (actv) {
            const float* hrg = sHsw + gL * 100;
            const float* wE = sWF + L * 100;             // even channel cA
            const float* wO = sWF + GWF_W2O + L * 100;   // odd channel cA+1
            #pragma unroll
            for (int u = 0; u < 12; ++u) {
                float4 hb0 = *(const float4*)(hrg + 8 * u);
                float4 hb1 = *(const float4*)(hrg + 8 * u + 4);
                float4 we0 = *(const float4*)(wE + 8 * u);
                float4 we1 = *(const float4*)(wE + 8 * u + 4);
                float4 wo0 = *(const float4*)(wO + 8 * u);
                float4 wo1 = *(const float4*)(wO + 8 * u + 4);
                accA = fmaf(hb0.x, we0.x, accA); accB = fmaf(hb0.x, wo0.x, accB);
                accA = fmaf(hb0.y, we0.y, accA); accB = fmaf(hb0.y, wo0.y, accB);
                accA = fmaf(hb0.z, we0.z, accA); accB = fmaf(hb0.z, wo0.z, accB);
                accA = fmaf(hb0.w, we0.w, accA); accB = fmaf(hb0.w, wo0.w, accB);
                accA = fmaf(hb1.x, we1.x, accA); accB = fmaf(hb1.x, wo1.x, accB);
                accA = fmaf(hb1.y, we1.y, accA); accB = fmaf(hb1.y, wo1.y, accB);
                accA = fmaf(hb1.z, we1.z, accA); accB = fmaf(hb1.z, wo1.z, accB);
                accA = fmaf(hb1.w, we1.w, accA); accB = fmaf(hb1.w, wo1.w, accB);
            }
            *(float2*)(out + (size_t)n * CC + cA) = make_float2(accA, accB);
        }
    }
}

extern "C" void kernel_launch(void* const* d_in, const int* in_sizes, int n_in,
                              void* d_out, int out_size, void* d_ws, size_t ws_size,
                              hipStream_t stream) {
    const float* feat  = (const float*)d_in[0];
    const float* coord = (const float*)d_in[1];
    const int*   ref   = (const int*)d_in[2];
    const float* Wq = (const float*)d_in[3],  *bq = (const float*)d_in[4],  *gq = (const float*)d_in[5],  *betaq = (const float*)d_in[6];
    const float* Wk = (const float*)d_in[7],  *bk = (const float*)d_in[8],  *gk = (const float*)d_in[9],  *betak = (const float*)d_in[10];
    const float* Wv = (const float*)d_in[11], *bv = (const float*)d_in[12];
    const float* Wp1 = (const float*)d_in[13], *bp1 = (const float*)d_in[14], *gp = (const float*)d_in[15], *betap = (const float*)d_in[16];
    const float* Wp2 = (const float*)d_in[17], *bp2 = (const float*)d_in[18];
    const float* Ww1 = (const float*)d_in[19], *bw1 = (const float*)d_in[20], *gw = (const float*)d_in[21], *betaw = (const float*)d_in[22];
    const float* Ww2 = (const float*)d_in[23], *bw2 = (const float*)d_in[24];

    const int N = in_sizes[0] / CC;   // 50000

    // workspace (~22.5 MB)
    float* wsf = (float*)d_ws;
    float* KW1 = wsf;                                  // N*8 f32
    float* qW1 = KW1 + (size_t)N * 8;                  // N*8 f32
    float* cvec = qW1 + (size_t)N * 8;                 // 6 (pad 32)
    float* gWF = cvec + 32;                            // 10200 (pad 10240)
    u16* WcatT = (u16*)(gWF + 10240);                  // 288*96 bf16
    u16* featB = WcatT + 288 * CC;                     // N*96 bf16
    u16* v_bf = featB + (size_t)N * CC;                // N*96 bf16

    const int total4 = N * CC / 4;
    prep_fcvt_kernel<<<dim3((total4 + 255) / 256), dim3(256), 0, stream>>>(
        feat, featB, total4,
        Wq, Wk, Wv, Wp2, Ww1, bp2, bw1, WcatT, gWF, cvec);

    gemm_qkv<<<dim3((N + 63) / 64), dim3(256), 0, stream>>>(
        featB, WcatT, bq, gq, betaq, bk, gk, betak, bv, Ww1,
        v_bf, KW1, qW1, N);

    attn_kernel<<<dim3(ABLK), dim3(256), 0, stream>>>(
        coord, ref, Wp1, bp1, gp, betap, bp2, gw, betaw, Ww2, bw2,
        v_bf, KW1, qW1, gWF, cvec, (float*)d_out, N);
}